// Round 16
// baseline (662.192 us; speedup 1.0000x reference)
//
#include <hip/hip_runtime.h>

// Problem constants (match reference setup_inputs)
#define NV     100000   // nodes
#define DD     128      // hidden dim
#define D2     256      // 2*D
#define EE     600000   // edges per relation
#define KK     3        // relations
#define LL     3        // layers
#define NFEAT  9
#define VOCABS 100

#define NBKT   196      // CSR buckets per relation (512 nodes each)
#define BCAP   8192     // bucket capacity (mean 3061, sigma 55 -> never hit)

typedef __attribute__((ext_vector_type(8))) short short8;
typedef __attribute__((ext_vector_type(4))) float f32x4;
typedef __attribute__((ext_vector_type(2))) float f32x2;
typedef __attribute__((ext_vector_type(4))) unsigned int uint4v;

// params: per layer l, params[l*4 + k] = softmax(alpha[l])[k]
// per-layer stats region (float offsets within stats + l*2048):
#define ZS(k)  ((k)*512)
#define ZQ(k)  ((k)*512 + 256)
#define HSUM   1536
#define HSQ    1664

// workspace byte offsets (hb padded by 8 zero rows -> zero-row gather trick)
#define HB_OFF   ((size_t)0)            // h (bf16)     (N+8)*128
#define ZIN_OFF  ((size_t)25700000)     // zin_k (bf16, FRAGMENT-TILED) 3 x N*128
#define HNB_OFF  ((size_t)102500000)    // h_next (bf16) N*128
#define O_BASE   ((size_t)128100000)

// zin fragment-tiled layout: granule (16B, 8 elems) of node n, slice (kt,g)
// lives at byte offset  k*NV*256 + (n>>4)*4096 + (kt*4+g)*256 + (n&15)*16.
// Consumers (stats3/gemm2f) load af[k][kt] at base + kt*1024 + lane*16:
// one fully-coalesced 1KB segment per wave.

__device__ __forceinline__ unsigned short f2bf(float f) {
    union { float f; unsigned int u; } v; v.f = f;
    return (unsigned short)((v.u + 0x7FFFu + ((v.u >> 16) & 1u)) >> 16);
}
__device__ __forceinline__ float bf2f(unsigned short u) {
    union { unsigned int u; float f; } v; v.u = ((unsigned int)u) << 16;
    return v.f;
}
// unpack a bf16 pair (one u32) to f32x2 {lo, hi}
__device__ __forceinline__ f32x2 up2(unsigned int v) {
    union { unsigned int u[2]; f32x2 f; } w;
    w.u[0] = v << 16;
    w.u[1] = v & 0xFFFF0000u;
    return w.f;
}

// h[n,d] = sum_f emb[f, x[n,f], d] -> bf16 ; rows NV..NV+7 zeroed (gather dummy)
__global__ void k_embed(const int* __restrict__ x, const float* __restrict__ emb,
                        unsigned short* __restrict__ hb) {
    int id = blockIdx.x*256 + threadIdx.x;
    int n = id >> 5, q = id & 31;
    if (n >= NV) {
        if (n < NV + 8) *(unsigned long long*)(hb + (size_t)n*DD + q*4) = 0ull;
        return;
    }
    const int* xr = x + n*NFEAT;
    f32x4 acc = {0.f,0.f,0.f,0.f};
    #pragma unroll
    for (int f = 0; f < NFEAT; ++f) {
        int idx = xr[f];
        acc += *(const f32x4*)(emb + ((size_t)(f*VOCABS + idx)*DD + q*4));
    }
    unsigned short pk[4];
    pk[0] = f2bf(acc[0]); pk[1] = f2bf(acc[1]); pk[2] = f2bf(acc[2]); pk[3] = f2bf(acc[3]);
    *(unsigned long long*)(hb + (size_t)n*DD + q*4) = *(unsigned long long*)pk;
}

// ---- CSR build: radix-binned; pairs packed to u32 (dstloc[9]<<17 | src[17]) ----
__global__ void kA_bin(const int* __restrict__ ke, int* __restrict__ cursor,
                       unsigned int* __restrict__ pairs) {
    __shared__ int hist[NBKT], excl[NBKT], ofs[NBKT], gbase[NBKT];
    __shared__ int sc[256];
    __shared__ unsigned int buf[4096];
    const int rel = blockIdx.y, t = threadIdx.x;
    const int e0 = blockIdx.x * 4096;
    const int cnt = min(4096, EE - e0);
    const int* srcA = ke + (size_t)(rel*2)*EE + e0;
    const int* dstA = ke + (size_t)(rel*2+1)*EE + e0;
    if (t < NBKT) hist[t] = 0;
    __syncthreads();
    for (int i = t; i < cnt; i += 256) atomicAdd(&hist[dstA[i] >> 9], 1);
    __syncthreads();
    const int hv = (t < NBKT) ? hist[t] : 0;
    sc[t] = hv;
    for (int off = 1; off < 256; off <<= 1) {
        __syncthreads();
        int v = (t >= off) ? sc[t-off] : 0;
        __syncthreads();
        sc[t] += v;
    }
    __syncthreads();
    if (t < NBKT) {
        excl[t] = sc[t] - hv;
        ofs[t]  = sc[t] - hv;
        if (hv > 0) gbase[t] = atomicAdd(&cursor[rel*NBKT + t], hv);
    }
    __syncthreads();
    for (int i = t; i < cnt; i += 256) {
        unsigned int s = (unsigned int)srcA[i], d = (unsigned int)dstA[i];
        int p = atomicAdd(&ofs[d >> 9], 1);
        buf[p] = ((d & 511u) << 17) | s;
    }
    __syncthreads();
    for (int i = t; i < cnt; i += 256) {
        unsigned int u = buf[i];
        // bucket recovered by binary search over excl boundaries (8 steps)
        int lo = 0, hi = NBKT - 1;
        #pragma unroll
        for (int s2 = 0; s2 < 8; ++s2) {
            int mid = (lo + hi + 1) >> 1;
            bool ge = (i >= excl[mid]);
            lo = ge ? mid : lo;
            hi = ge ? hi : mid - 1;
        }
        const int b = lo;
        int pos = gbase[b] + (i - excl[b]);
        if (pos < BCAP) pairs[(size_t)(rel*NBKT + b)*BCAP + pos] = u;
    }
}

__global__ void kB_scan(const int* __restrict__ cursor, int* __restrict__ ebase) {
    __shared__ int sc[256];
    const int t = threadIdx.x;
    for (int rel = 0; rel < KK; ++rel) {
        int hv = (t < NBKT) ? min(cursor[rel*NBKT + t], BCAP) : 0;
        sc[t] = hv;
        for (int off = 1; off < 256; off <<= 1) {
            __syncthreads();
            int v = (t >= off) ? sc[t-off] : 0;
            __syncthreads();
            sc[t] += v;
        }
        __syncthreads();
        if (t < NBKT) ebase[rel*NBKT + t] = sc[t] - hv;
        __syncthreads();
    }
}

__global__ void kB_fill(const unsigned int* __restrict__ pairs, const int* __restrict__ cursor,
                        const int* __restrict__ ebase, int* __restrict__ rp,
                        int* __restrict__ col) {
    __shared__ int h2[512], excl[512], cur[512], sc[256];
    const int b = blockIdx.x, rel = blockIdx.y, t = threadIdx.x;
    const int lo = b * 512;
    const int cnt = min(cursor[rel*NBKT + b], BCAP);
    const int base = ebase[rel*NBKT + b];
    const unsigned int* P = pairs + (size_t)(rel*NBKT + b)*BCAP;
    h2[t] = 0; h2[t+256] = 0; cur[t] = 0; cur[t+256] = 0;
    __syncthreads();
    for (int i = t; i < cnt; i += 256) atomicAdd(&h2[P[i] >> 17], 1);
    __syncthreads();
    const int a0 = h2[2*t], a1 = h2[2*t+1];
    sc[t] = a0 + a1;
    for (int off = 1; off < 256; off <<= 1) {
        __syncthreads();
        int v = (t >= off) ? sc[t-off] : 0;
        __syncthreads();
        sc[t] += v;
    }
    __syncthreads();
    const int e2 = sc[t] - (a0 + a1);
    excl[2*t] = e2; excl[2*t+1] = e2 + a0;
    __syncthreads();
    for (int tt = t; tt < 512; tt += 256) {
        int n = lo + tt;
        if (n <= NV) rp[(size_t)rel*(NV+1) + n] = base + excl[tt];
    }
    for (int i = t; i < cnt; i += 256) {
        unsigned int u = P[i];
        int r = (int)(u >> 17);
        int p = atomicAdd(&cur[r], 1);
        col[(size_t)rel*EE + base + excl[r] + p] = (int)(u & 0x1FFFFu);
    }
}

// ALL layers at once: pack W1/W2 to bf16 MFMA fragments; softmax(alpha[l]).
__global__ void k_prep_all(const float* __restrict__ W1, const float* __restrict__ W2,
                           const float* __restrict__ alpha,
                           unsigned short* __restrict__ w1f, unsigned short* __restrict__ w2f,
                           float* __restrict__ params) {
    const int l = blockIdx.y;
    int id = blockIdx.x*256 + threadIdx.x;
    if (id == 0) {
        float a0 = alpha[l*KK+0], a1 = alpha[l*KK+1], a2 = alpha[l*KK+2];
        float m = fmaxf(a0, fmaxf(a1, a2));
        float e0 = expf(a0-m), e1 = expf(a1-m), e2 = expf(a2-m);
        float inv = 1.f/(e0+e1+e2);
        params[l*4+0] = e0*inv; params[l*4+1] = e1*inv; params[l*4+2] = e2*inv;
    }
    if (id < 4096) {                       // W1: [128][256]
        int kt = id >> 10, nt = (id >> 6) & 15, lane = id & 63;
        int r = lane & 15, g = lane >> 4;
        const float* Wl = W1 + (size_t)l*DD*D2;
        #pragma unroll
        for (int e = 0; e < 8; ++e) {
            int kk = kt*32 + g*8 + e, c = nt*16 + r;
            w1f[(size_t)l*32768 + (size_t)id*8 + e] = f2bf(Wl[(size_t)kk*D2 + c]);
        }
    } else if (id < 8192) {                // W2: [256][128]
        int id2 = id - 4096;
        int kt = id2 >> 9, nt = (id2 >> 6) & 7, lane = id2 & 63;
        int r = lane & 15, g = lane >> 4;
        const float* Wl = W2 + (size_t)l*D2*DD;
        #pragma unroll
        for (int e = 0; e < 8; ++e) {
            int kk = kt*32 + g*8 + e, c = nt*16 + r;
            w2f[(size_t)l*32768 + (size_t)id2*8 + e] = f2bf(Wl[(size_t)kk*DD + c]);
        }
    }
}

// zin_k[n,:] = bf16( (1+eps)*h[n,:] + sum_{j->n,k} h[j,:] )  for all 3 relations.
// One wave per node (n wave-uniform -> SGPR); writes FRAGMENT-TILED zin.
// MERGED relation loop: all 3 relations advance together to max_dc with 6 row
// loads in flight per iteration and ZERO predicates -- exhausted relations'
// shfl indices land on cv[k]=NV (the zero row), adding exact 0.
__global__ void k_gather3(const unsigned short* __restrict__ hb, const int* __restrict__ rp,
                          const int* __restrict__ col, const float* __restrict__ epsp,
                          unsigned short* __restrict__ zin) {
    int gid = blockIdx.x*256 + threadIdx.x;
    int n0 = gid >> 6;
    if (n0 >= NV) return;
    const int n = __builtin_amdgcn_readfirstlane(n0);   // wave-uniform -> SGPR
    const int lane = threadIdx.x & 63;
    const int q = lane >> 4, r = lane & 15;
    const int r16 = r << 4;
    const char* hbase = (const char*)hb;
    const float epsv = 1.0f + epsp[0];
    const uint4v sv = *(const uint4v*)(hbase + (((unsigned)n << 8) + r16));
    int b0[KK], dg[KK], cv[KK];
    #pragma unroll
    for (int k = 0; k < KK; ++k) {
        int a = rp[k*(NV+1) + n];
        int b = rp[k*(NV+1) + n + 1];
        b0[k] = a; dg[k] = b - a;
        cv[k] = (lane < dg[k]) ? col[(size_t)k*EE + a + lane] : NV;  // NV = zero row
    }
    f32x2 acc[KK][4];
    #pragma unroll
    for (int k = 0; k < KK; ++k)
        #pragma unroll
        for (int c = 0; c < 4; ++c) acc[k][c] = (f32x2){0.f, 0.f};
    const int dc0 = min(dg[0], 64), dc1 = min(dg[1], 64), dc2 = min(dg[2], 64);
    const int mdc = max(dc0, max(dc1, dc2));    // wave-uniform
    for (int base = 0; base < mdc; base += 8) {
        // 6 independent row loads in flight (shfl idx <= 63 always; lanes all
        // active; over-run indices hit the zero row -> accumulate 0)
        int s0a = __shfl(cv[0], base + q),     s0b = __shfl(cv[0], base + q + 4);
        int s1a = __shfl(cv[1], base + q),     s1b = __shfl(cv[1], base + q + 4);
        int s2a = __shfl(cv[2], base + q),     s2b = __shfl(cv[2], base + q + 4);
        uint4v v0a = *(const uint4v*)(hbase + (((unsigned)s0a << 8) + r16));
        uint4v v0b = *(const uint4v*)(hbase + (((unsigned)s0b << 8) + r16));
        uint4v v1a = *(const uint4v*)(hbase + (((unsigned)s1a << 8) + r16));
        uint4v v1b = *(const uint4v*)(hbase + (((unsigned)s1b << 8) + r16));
        uint4v v2a = *(const uint4v*)(hbase + (((unsigned)s2a << 8) + r16));
        uint4v v2b = *(const uint4v*)(hbase + (((unsigned)s2b << 8) + r16));
        #pragma unroll
        for (int c = 0; c < 4; ++c) {
            acc[0][c] += up2(v0a[c]); acc[0][c] += up2(v0b[c]);
            acc[1][c] += up2(v1a[c]); acc[1][c] += up2(v1b[c]);
            acc[2][c] += up2(v2a[c]); acc[2][c] += up2(v2b[c]);
        }
    }
    // deg > 64 tails: direct col loads (no cross-lane ops; rare)
    #pragma unroll
    for (int k = 0; k < KK; ++k) {
        for (int j = b0[k] + 64 + q; j < b0[k] + dg[k]; j += 4) {
            int s0 = col[(size_t)k*EE + j];
            uint4v v0 = *(const uint4v*)(hbase + (((unsigned)s0 << 8) + r16));
            #pragma unroll
            for (int c = 0; c < 4; ++c) acc[k][c] += up2(v0[c]);
        }
    }
    #pragma unroll
    for (int k = 0; k < KK; ++k) {
        #pragma unroll
        for (int c = 0; c < 4; ++c) {
            acc[k][c][0] += __shfl_xor(acc[k][c][0], 16);
            acc[k][c][1] += __shfl_xor(acc[k][c][1], 16);
            acc[k][c][0] += __shfl_xor(acc[k][c][0], 32);
            acc[k][c][1] += __shfl_xor(acc[k][c][1], 32);
        }
    }
    if (q == 0) {
        // fragment-tiled store: granule r of node n ->
        //   k*NV*256 + (n>>4)*4096 + r*256 + (n&15)*16
        const unsigned dsto = (((unsigned)n >> 4) << 12) + ((unsigned)r << 8)
                            + (((unsigned)n & 15u) << 4);
        #pragma unroll
        for (int k = 0; k < KK; ++k) {
            uint4v pk;
            #pragma unroll
            for (int c = 0; c < 4; ++c) {
                f32x2 s2 = up2(sv[c]);
                float lo = acc[k][c][0] + epsv * s2[0];
                float hi = acc[k][c][1] + epsv * s2[1];
                unsigned int pko;
                asm("v_cvt_pk_bf16_f32 %0, %1, %2" : "=v"(pko) : "v"(lo), "v"(hi));
                pk[c] = pko;
            }
            *(uint4v*)((char*)zin + (size_t)k*NV*256 + dsto) = pk;
        }
    }
}

// BN1 stats of z1_k = zin_k @ W1 for ALL relations (looped inside; W1 staged
// once per block). Grid 256 so staging traffic is 256x64KB.
__launch_bounds__(256, 2)
__global__ void k_stats3(const unsigned short* __restrict__ zin,
                         const unsigned short* __restrict__ w1f,
                         float* __restrict__ statsL) {
    __shared__ __align__(16) unsigned short bfr1[32768];  // 64KB W1 frags
    __shared__ float scf[1024];
    const int t = threadIdx.x;
    for (int i = t; i < 4096; i += 256)
        *(uint4v*)(bfr1 + i*8) = *(const uint4v*)(w1f + i*8);
    const int lane = t & 63, w = t >> 6;
    const int r_ = lane & 15, g = lane >> 4;
    const int rt = w & 1, ch = w >> 1;
    __syncthreads();
    for (int krel = 0; krel < KK; ++krel) {
        const char* zk = (const char*)zin + (size_t)krel*NV*256;
        float ssum[8] = {0,0,0,0,0,0,0,0};
        float ssq[8]  = {0,0,0,0,0,0,0,0};
        for (int tile = blockIdx.x; tile < NV/32; tile += gridDim.x) {
            short8 af[4];
            #pragma unroll
            for (int kt = 0; kt < 4; ++kt)
                af[kt] = *(const short8*)(zk + (size_t)(tile*2 + rt)*4096 + kt*1024 + lane*16);
            #pragma unroll
            for (int ct = 0; ct < 8; ++ct) {
                const int ntg = ch*8 + ct;
                f32x4 c = {0.f,0.f,0.f,0.f};
                #pragma unroll
                for (int kt = 0; kt < 4; ++kt) {
                    short8 b = *(const short8*)(bfr1 + ((size_t)((kt*16 + ntg)*64 + lane))*8);
                    c = __builtin_amdgcn_mfma_f32_16x16x32_bf16(af[kt], b, c, 0, 0, 0);
                }
                float s = c[0]+c[1]+c[2]+c[3];
                float q = c[0]*c[0]+c[1]*c[1]+c[2]*c[2]+c[3]*c[3];
                s += __shfl_xor(s, 16); q += __shfl_xor(q, 16);
                s += __shfl_xor(s, 32); q += __shfl_xor(q, 32);
                ssum[ct] += s; ssq[ct] += q;
            }
        }
        __syncthreads();   // prior krel's atomics done reading scf
        if (g == 0) {
            #pragma unroll
            for (int ct = 0; ct < 8; ++ct) {
                const int colc = (ch*8 + ct)*16 + r_;
                scf[rt*256 + colc]       = ssum[ct];
                scf[512 + rt*256 + colc] = ssq[ct];
            }
        }
        __syncthreads();
        atomicAdd(statsL + ZS(krel) + t, scf[t]       + scf[256 + t]);
        atomicAdd(statsL + ZQ(krel) + t, scf[512 + t] + scf[768 + t]);
    }
}

// hn = [ sum_k relu(A''_k (zin_k @ W1) + B''_k) ] @ W2 + hn column stats.
// R5-proven structure (8 waves, W1+W2 LDS 128KB, single 16KB yt); af loads
// 1KB coalesced via the fragment-tiled zin layout. BN1 affine inline.
__launch_bounds__(512, 2)
__global__ void k_gemm2f(const unsigned short* __restrict__ zin,
                         const unsigned short* __restrict__ w1f,
                         const unsigned short* __restrict__ w2f,
                         const float* __restrict__ g1l, const float* __restrict__ be1l,
                         const float* __restrict__ params,
                         float* __restrict__ statsL,
                         unsigned short* __restrict__ hnb) {
    __shared__ __align__(16) unsigned short bfr1[32768];  // 64KB W1 frags
    __shared__ __align__(16) unsigned short bfr2[32768];  // 64KB W2 frags
    __shared__ __align__(16) unsigned char yt[16384];     // 32 x 256 bf16, swizzled
    const int t = threadIdx.x;
    for (int i = t; i < 4096; i += 512)
        *(uint4v*)(bfr1 + i*8) = *(const uint4v*)(w1f + i*8);
    for (int i = t; i < 4096; i += 512)
        *(uint4v*)(bfr2 + i*8) = *(const uint4v*)(w2f + i*8);
    const int lane = t & 63, w = t >> 6;          // 8 waves
    const int r_ = lane & 15, g = lane >> 4;
    const int rt = w & 1, ch = w >> 1;            // rt: row half, ch: col quarter
    const int arow = rt*16 + r_;
    // BN1 affine (a_k folded) computed inline from raw column stats
    float pa1[KK][4], pb1[KK][4];
    #pragma unroll
    for (int k = 0; k < KK; ++k) {
        const float ak = params[k];
        #pragma unroll
        for (int ct = 0; ct < 4; ++ct) {
            const int colc = (ch*4 + ct)*16 + r_;
            float mu  = statsL[ZS(k) + colc] * (1.0f/NV);
            float var = statsL[ZQ(k) + colc] * (1.0f/NV) - mu*mu;
            float A = g1l[colc] * rsqrtf(var + 1e-5f);
            pa1[k][ct] = ak * A;
            pb1[k][ct] = ak * (be1l[colc] - mu*A);
        }
    }
    __syncthreads();
    float ssum[2] = {0,0}, ssq[2] = {0,0};
    for (int tile = blockIdx.x; tile < NV/32; tile += gridDim.x) {
        const int row0 = tile*32;
        // phase 1: y = sum_k relu(BN1_k(zin_k @ W1)); af coalesced 1KB loads
        f32x4 y[4];
        #pragma unroll
        for (int ct = 0; ct < 4; ++ct) y[ct] = (f32x4){0.f,0.f,0.f,0.f};
        short8 af[KK][4];
        #pragma unroll
        for (int k = 0; k < KK; ++k) {
            #pragma unroll
            for (int kt = 0; kt < 4; ++kt)
                af[k][kt] = *(const short8*)((const char*)zin + (size_t)k*NV*256
                              + (size_t)(tile*2 + rt)*4096 + kt*1024 + lane*16);
        }
        #pragma unroll
        for (int k = 0; k < KK; ++k) {
            #pragma unroll
            for (int ct = 0; ct < 4; ++ct) {
                const int ntg = ch*4 + ct;
                f32x4 c = {0.f,0.f,0.f,0.f};
                #pragma unroll
                for (int kt = 0; kt < 4; ++kt) {
                    short8 b = *(const short8*)(bfr1 + ((size_t)((kt*16 + ntg)*64 + lane))*8);
                    c = __builtin_amdgcn_mfma_f32_16x16x32_bf16(af[k][kt], b, c, 0, 0, 0);
                }
                #pragma unroll
                for (int reg = 0; reg < 4; ++reg)
                    y[ct][reg] += fmaxf(pa1[k][ct]*c[reg] + pb1[k][ct], 0.0f);
            }
        }
        __syncthreads();   // prev phase2 done reading yt
        #pragma unroll
        for (int ct = 0; ct < 4; ++ct) {
            const int col2 = ((ch*4 + ct)*16 + r_)*2;
            #pragma unroll
            for (int reg = 0; reg < 4; ++reg) {
                const int row = rt*16 + g*4 + reg;
                *(unsigned short*)(yt + row*512 + (col2 ^ ((row & 15) << 4))) = f2bf(y[ct][reg]);
            }
        }
        __syncthreads();
        // phase 2: hn = y @ W2 (W2 from LDS)
        short8 ya[8];
        #pragma unroll
        for (int kt = 0; kt < 8; ++kt)
            ya[kt] = *(const short8*)(yt + arow*512 + ((kt*64 + g*16) ^ ((arow & 15) << 4)));
        #pragma unroll
        for (int ct2 = 0; ct2 < 2; ++ct2) {
            const int ntg2 = ch*2 + ct2;
            f32x4 c = {0.f,0.f,0.f,0.f};
            #pragma unroll
            for (int kt = 0; kt < 8; ++kt) {
                short8 b = *(const short8*)(bfr2 + ((size_t)((kt*8 + ntg2)*64 + lane))*8);
                c = __builtin_amdgcn_mfma_f32_16x16x32_bf16(ya[kt], b, c, 0, 0, 0);
            }
            unsigned short* hp = hnb + (size_t)(row0 + rt*16 + g*4)*DD + ntg2*16 + r_;
            float ps = 0.0f, pq = 0.0f;
            #pragma unroll
            for (int reg = 0; reg < 4; ++reg) {
                float xv = c[reg];
                hp[(size_t)reg*DD] = f2bf(xv);
                ps += xv; pq += xv*xv;
            }
            ps += __shfl_xor(ps, 16); pq += __shfl_xor(pq, 16);
            ps += __shfl_xor(ps, 32); pq += __shfl_xor(pq, 32);
            ssum[ct2] += ps; ssq[ct2] += pq;
        }
    }
    // flush hn column stats (reuse yt; wave w covers cols ch*32 .. ch*32+31)
    __syncthreads();
    float* scf = (float*)yt;
    if (g == 0) {
        #pragma unroll
        for (int ct2 = 0; ct2 < 2; ++ct2) {
            scf[w*32 + ct2*16 + r_]       = ssum[ct2];
            scf[256 + w*32 + ct2*16 + r_] = ssq[ct2];
        }
    }
    __syncthreads();
    if (t < 128) {
        const int chc = t >> 5, idx = t & 31;
        float s = 0.0f, q = 0.0f;
        #pragma unroll
        for (int rr = 0; rr < 2; ++rr) {
            s += scf[(chc*2 + rr)*32 + idx];
            q += scf[256 + (chc*2 + rr)*32 + idx];
        }
        atomicAdd(statsL + HSUM + t, s);
        atomicAdd(statsL + HSQ + t, q);
    }
}

// mid layers: h(bf16) = relu(BN2(hn)); BN2 affine computed inline from stats
__global__ void k_bnapply_mid(const unsigned short* __restrict__ hnb,
                              const float* __restrict__ statsL,
                              const float* __restrict__ bng, const float* __restrict__ bnb,
                              unsigned short* __restrict__ hb) {
    int id = blockIdx.x*256 + threadIdx.x;       // 6250 blocks * 8 elems
    const int col0 = (id & 15)*8;
    short8 v = *(const short8*)(hnb + (size_t)id*8);
    short8 o;
    #pragma unroll
    for (int j = 0; j < 8; ++j) {
        const int c = col0 + j;
        float mu  = statsL[HSUM + c] * (1.0f/NV);
        float var = statsL[HSQ + c] * (1.0f/NV) - mu*mu;
        float A = bng[c] * rsqrtf(var + 1e-5f);
        float B = bnb[c] - mu*A;
        o[j] = (short)f2bf(fmaxf(A*bf2f((unsigned short)v[j]) + B, 0.0f));
    }
    *(short8*)(hb + (size_t)id*8) = o;
}

// final layer: d_out(f32) = relu(BN2(hn))
__global__ void k_bnapply_fin(const unsigned short* __restrict__ hnb,
                              const float* __restrict__ statsL,
                              const float* __restrict__ bng, const float* __restrict__ bnb,
                              float* __restrict__ out) {
    int id = blockIdx.x*256 + threadIdx.x;
    const int col0 = (id & 15)*8;
    short8 v = *(const short8*)(hnb + (size_t)id*8);
    f32x4 o0, o1;
    #pragma unroll
    for (int j = 0; j < 8; ++j) {
        const int c = col0 + j;
        float mu  = statsL[HSUM + c] * (1.0f/NV);
        float var = statsL[HSQ + c] * (1.0f/NV) - mu*mu;
        float A = bng[c] * rsqrtf(var + 1e-5f);
        float B = bnb[c] - mu*A;
        float r = fmaxf(A*bf2f((unsigned short)v[j]) + B, 0.0f);
        if (j < 4) o0[j] = r; else o1[j-4] = r;
    }
    *(f32x4*)(out + (size_t)id*8)     = o0;
    *(f32x4*)(out + (size_t)id*8 + 4) = o1;
}

extern "C" void kernel_launch(void* const* d_in, const int* in_sizes, int n_in,
                              void* d_out, int out_size, void* d_ws, size_t ws_size,
                              hipStream_t stream) {
    const int*   x     = (const int*)d_in[0];
    const int*   ke    = (const int*)d_in[1];
    const float* emb   = (const float*)d_in[2];
    const float* W1    = (const float*)d_in[3];
    // d_in[4] = b1: per-column shift cancels exactly through training-mode BN
    const float* g1    = (const float*)d_in[5];
    const float* be1   = (const float*)d_in[6];
    const float* W2    = (const float*)d_in[7];
    // d_in[8] = b2: cancels through final BN (softmax weights sum to 1)
    const float* eps   = (const float*)d_in[9];
    const float* alpha = (const float*)d_in[10];
    const float* bng   = (const float*)d_in[11];
    const float* bnb   = (const float*)d_in[12];

    char* ws = (char*)d_ws;
    unsigned short* hb     = (unsigned short*)(ws + HB_OFF);
    unsigned short* zin    = (unsigned short*)(ws + ZIN_OFF);   // 3 buffers, tiled
    unsigned short* hnb    = (unsigned short*)(ws + HNB_OFF);
    size_t o = O_BASE;
    unsigned short* w1f    = (unsigned short*)(ws + o);          o += 3*65536;
    unsigned short* w2f    = (unsigned short*)(ws + o);          o += 3*65536;
    float*          stats  = (float*)(ws + o);                   o += 32768;  // 3 x 2048 floats
    float*          params = (float*)(ws + o);                   o += 4096;
    int*            rp     = (int*)(ws + o);                     o += 1200128;
    int*            col    = (int*)(ws + o);                     o += 7200000;
    int*            cur    = (int*)(ws + o);                     o += 4096;
    int*            ebase  = (int*)(ws + o);                     o += 4096;
    unsigned int*   pairs  = (unsigned int*)(ws + ZIN_OFF);      // aliased (pre-zin)

    // AtomEncoder (+ zero-pad rows NV..NV+7 for the gather dummy row)
    k_embed<<<12501, 256, 0, stream>>>(x, emb, hb);

    // Weight prep for ALL layers (single dispatch, off the per-layer path)
    k_prep_all<<<dim3(32, LL), 256, 0, stream>>>(W1, W2, alpha, w1f, w2f, params);

    // CSR build (shared by all layers; uses pairs alias before any zin write)
    hipMemsetAsync(cur, 0, KK*NBKT*sizeof(int), stream);
    hipMemsetAsync(stats, 0, 3*2048*sizeof(float), stream);   // all layers' stats
    kA_bin<<<dim3(147, KK), 256, 0, stream>>>(ke, cur, pairs);
    kB_scan<<<1, 256, 0, stream>>>(cur, ebase);
    kB_fill<<<dim3(NBKT, KK), 256, 0, stream>>>(pairs, cur, ebase, rp, col);

    for (int l = 0; l < LL; ++l) {
        float* statsL = stats + (size_t)l*2048;
        unsigned short* w1fl = w1f + (size_t)l*32768;
        unsigned short* w2fl = w2f + (size_t)l*32768;
        k_gather3<<<25000, 256, 0, stream>>>(hb, rp, col, eps + l, zin);
        k_stats3<<<256, 256, 0, stream>>>(zin, w1fl, statsL);
        k_gemm2f<<<256, 512, 0, stream>>>(zin, w1fl, w2fl, g1 + l*D2, be1 + l*D2,
                                          params + l*4, statsL, hnb);
        if (l < LL-1) k_bnapply_mid<<<6250, 256, 0, stream>>>(hnb, statsL,
                                                              bng + l*DD, bnb + l*DD, hb);
        else          k_bnapply_fin<<<6250, 256, 0, stream>>>(hnb, statsL,
                                                              bng + l*DD, bnb + l*DD,
                                                              (float*)d_out);
    }
}

// Round 17
// 653.100 us; speedup vs baseline: 1.0139x; 1.0139x over previous
//
#include <hip/hip_runtime.h>

// Problem constants (match reference setup_inputs)
#define NV     100000   // nodes
#define DD     128      // hidden dim
#define D2     256      // 2*D
#define EE     600000   // edges per relation
#define KK     3        // relations
#define LL     3        // layers
#define NFEAT  9
#define VOCABS 100

#define NBKT   196      // CSR buckets per relation (512 nodes each)
#define BCAP   8192     // bucket capacity (mean 3061, sigma 55 -> never hit)

typedef __attribute__((ext_vector_type(8))) short short8;
typedef __attribute__((ext_vector_type(4))) float f32x4;
typedef __attribute__((ext_vector_type(2))) float f32x2;
typedef __attribute__((ext_vector_type(4))) unsigned int uint4v;

// params: per layer l, params[l*4 + k] = softmax(alpha[l])[k]
// per-layer stats region (float offsets within stats + l*2048):
#define ZS(k)  ((k)*512)
#define ZQ(k)  ((k)*512 + 256)
#define HSUM   1536
#define HSQ    1664

// workspace byte offsets (hb padded by 8 zero rows -> zero-row gather trick)
#define HB_OFF   ((size_t)0)            // h (bf16)     (N+8)*128
#define ZIN_OFF  ((size_t)25700000)     // zin_k (bf16, FRAGMENT-TILED) 3 x N*128
#define HNB_OFF  ((size_t)102500000)    // h_next (bf16) N*128
#define O_BASE   ((size_t)128100000)

// zin fragment-tiled layout: granule (16B, 8 elems) of node n, slice (kt,g)
// lives at byte offset  k*NV*256 + (n>>4)*4096 + (kt*4+g)*256 + (n&15)*16.
// Consumers (stats3/gemm2f) load af[k][kt] at base + kt*1024 + lane*16:
// one fully-coalesced 1KB segment per wave.

__device__ __forceinline__ unsigned short f2bf(float f) {
    union { float f; unsigned int u; } v; v.f = f;
    return (unsigned short)((v.u + 0x7FFFu + ((v.u >> 16) & 1u)) >> 16);
}
__device__ __forceinline__ float bf2f(unsigned short u) {
    union { unsigned int u; float f; } v; v.u = ((unsigned int)u) << 16;
    return v.f;
}
// unpack a bf16 pair (one u32) to f32x2 {lo, hi}
__device__ __forceinline__ f32x2 up2(unsigned int v) {
    union { unsigned int u[2]; f32x2 f; } w;
    w.u[0] = v << 16;
    w.u[1] = v & 0xFFFF0000u;
    return w.f;
}

// h[n,d] = sum_f emb[f, x[n,f], d] -> bf16 ; rows NV..NV+7 zeroed (gather dummy)
__global__ void k_embed(const int* __restrict__ x, const float* __restrict__ emb,
                        unsigned short* __restrict__ hb) {
    int id = blockIdx.x*256 + threadIdx.x;
    int n = id >> 5, q = id & 31;
    if (n >= NV) {
        if (n < NV + 8) *(unsigned long long*)(hb + (size_t)n*DD + q*4) = 0ull;
        return;
    }
    const int* xr = x + n*NFEAT;
    f32x4 acc = {0.f,0.f,0.f,0.f};
    #pragma unroll
    for (int f = 0; f < NFEAT; ++f) {
        int idx = xr[f];
        acc += *(const f32x4*)(emb + ((size_t)(f*VOCABS + idx)*DD + q*4));
    }
    unsigned short pk[4];
    pk[0] = f2bf(acc[0]); pk[1] = f2bf(acc[1]); pk[2] = f2bf(acc[2]); pk[3] = f2bf(acc[3]);
    *(unsigned long long*)(hb + (size_t)n*DD + q*4) = *(unsigned long long*)pk;
}

// ---- CSR build: radix-binned; pairs packed to u32 (dstloc[9]<<17 | src[17]) ----
__global__ void kA_bin(const int* __restrict__ ke, int* __restrict__ cursor,
                       unsigned int* __restrict__ pairs) {
    __shared__ int hist[NBKT], excl[NBKT], ofs[NBKT], gbase[NBKT];
    __shared__ int sc[256];
    __shared__ unsigned int buf[4096];
    const int rel = blockIdx.y, t = threadIdx.x;
    const int e0 = blockIdx.x * 4096;
    const int cnt = min(4096, EE - e0);
    const int* srcA = ke + (size_t)(rel*2)*EE + e0;
    const int* dstA = ke + (size_t)(rel*2+1)*EE + e0;
    if (t < NBKT) hist[t] = 0;
    __syncthreads();
    for (int i = t; i < cnt; i += 256) atomicAdd(&hist[dstA[i] >> 9], 1);
    __syncthreads();
    const int hv = (t < NBKT) ? hist[t] : 0;
    sc[t] = hv;
    for (int off = 1; off < 256; off <<= 1) {
        __syncthreads();
        int v = (t >= off) ? sc[t-off] : 0;
        __syncthreads();
        sc[t] += v;
    }
    __syncthreads();
    if (t < NBKT) {
        excl[t] = sc[t] - hv;
        ofs[t]  = sc[t] - hv;
        if (hv > 0) gbase[t] = atomicAdd(&cursor[rel*NBKT + t], hv);
    }
    __syncthreads();
    for (int i = t; i < cnt; i += 256) {
        unsigned int s = (unsigned int)srcA[i], d = (unsigned int)dstA[i];
        int p = atomicAdd(&ofs[d >> 9], 1);
        buf[p] = ((d & 511u) << 17) | s;
    }
    __syncthreads();
    for (int i = t; i < cnt; i += 256) {
        unsigned int u = buf[i];
        // bucket recovered by binary search over excl boundaries (8 steps)
        int lo = 0, hi = NBKT - 1;
        #pragma unroll
        for (int s2 = 0; s2 < 8; ++s2) {
            int mid = (lo + hi + 1) >> 1;
            bool ge = (i >= excl[mid]);
            lo = ge ? mid : lo;
            hi = ge ? hi : mid - 1;
        }
        const int b = lo;
        int pos = gbase[b] + (i - excl[b]);
        if (pos < BCAP) pairs[(size_t)(rel*NBKT + b)*BCAP + pos] = u;
    }
}

__global__ void kB_scan(const int* __restrict__ cursor, int* __restrict__ ebase) {
    __shared__ int sc[256];
    const int t = threadIdx.x;
    for (int rel = 0; rel < KK; ++rel) {
        int hv = (t < NBKT) ? min(cursor[rel*NBKT + t], BCAP) : 0;
        sc[t] = hv;
        for (int off = 1; off < 256; off <<= 1) {
            __syncthreads();
            int v = (t >= off) ? sc[t-off] : 0;
            __syncthreads();
            sc[t] += v;
        }
        __syncthreads();
        if (t < NBKT) ebase[rel*NBKT + t] = sc[t] - hv;
        __syncthreads();
    }
}

__global__ void kB_fill(const unsigned int* __restrict__ pairs, const int* __restrict__ cursor,
                        const int* __restrict__ ebase, int* __restrict__ rp,
                        int* __restrict__ col) {
    __shared__ int h2[512], excl[512], cur[512], sc[256];
    const int b = blockIdx.x, rel = blockIdx.y, t = threadIdx.x;
    const int lo = b * 512;
    const int cnt = min(cursor[rel*NBKT + b], BCAP);
    const int base = ebase[rel*NBKT + b];
    const unsigned int* P = pairs + (size_t)(rel*NBKT + b)*BCAP;
    h2[t] = 0; h2[t+256] = 0; cur[t] = 0; cur[t+256] = 0;
    __syncthreads();
    for (int i = t; i < cnt; i += 256) atomicAdd(&h2[P[i] >> 17], 1);
    __syncthreads();
    const int a0 = h2[2*t], a1 = h2[2*t+1];
    sc[t] = a0 + a1;
    for (int off = 1; off < 256; off <<= 1) {
        __syncthreads();
        int v = (t >= off) ? sc[t-off] : 0;
        __syncthreads();
        sc[t] += v;
    }
    __syncthreads();
    const int e2 = sc[t] - (a0 + a1);
    excl[2*t] = e2; excl[2*t+1] = e2 + a0;
    __syncthreads();
    for (int tt = t; tt < 512; tt += 256) {
        int n = lo + tt;
        if (n <= NV) rp[(size_t)rel*(NV+1) + n] = base + excl[tt];
    }
    for (int i = t; i < cnt; i += 256) {
        unsigned int u = P[i];
        int r = (int)(u >> 17);
        int p = atomicAdd(&cur[r], 1);
        col[(size_t)rel*EE + base + excl[r] + p] = (int)(u & 0x1FFFFu);
    }
}

// ALL layers at once: pack W1/W2 to bf16 MFMA fragments; softmax(alpha[l]).
__global__ void k_prep_all(const float* __restrict__ W1, const float* __restrict__ W2,
                           const float* __restrict__ alpha,
                           unsigned short* __restrict__ w1f, unsigned short* __restrict__ w2f,
                           float* __restrict__ params) {
    const int l = blockIdx.y;
    int id = blockIdx.x*256 + threadIdx.x;
    if (id == 0) {
        float a0 = alpha[l*KK+0], a1 = alpha[l*KK+1], a2 = alpha[l*KK+2];
        float m = fmaxf(a0, fmaxf(a1, a2));
        float e0 = expf(a0-m), e1 = expf(a1-m), e2 = expf(a2-m);
        float inv = 1.f/(e0+e1+e2);
        params[l*4+0] = e0*inv; params[l*4+1] = e1*inv; params[l*4+2] = e2*inv;
    }
    if (id < 4096) {                       // W1: [128][256]
        int kt = id >> 10, nt = (id >> 6) & 15, lane = id & 63;
        int r = lane & 15, g = lane >> 4;
        const float* Wl = W1 + (size_t)l*DD*D2;
        #pragma unroll
        for (int e = 0; e < 8; ++e) {
            int kk = kt*32 + g*8 + e, c = nt*16 + r;
            w1f[(size_t)l*32768 + (size_t)id*8 + e] = f2bf(Wl[(size_t)kk*D2 + c]);
        }
    } else if (id < 8192) {                // W2: [256][128]
        int id2 = id - 4096;
        int kt = id2 >> 9, nt = (id2 >> 6) & 7, lane = id2 & 63;
        int r = lane & 15, g = lane >> 4;
        const float* Wl = W2 + (size_t)l*D2*DD;
        #pragma unroll
        for (int e = 0; e < 8; ++e) {
            int kk = kt*32 + g*8 + e, c = nt*16 + r;
            w2f[(size_t)l*32768 + (size_t)id2*8 + e] = f2bf(Wl[(size_t)kk*DD + c]);
        }
    }
}

// zin_k[n,:] = bf16( (1+eps)*h[n,:] + sum_{j->n,k} h[j,:] )  for all 3 relations.
// One wave per node (n wave-uniform -> SGPR); writes FRAGMENT-TILED zin.
// Sequential relation loop (R15-proven: 74% occupancy at VGPR 28; merged-loop
// variant raised VGPR to 44, dropped occupancy to 46% and was net slower).
__global__ void k_gather3(const unsigned short* __restrict__ hb, const int* __restrict__ rp,
                          const int* __restrict__ col, const float* __restrict__ epsp,
                          unsigned short* __restrict__ zin) {
    int gid = blockIdx.x*256 + threadIdx.x;
    int n0 = gid >> 6;
    if (n0 >= NV) return;
    const int n = __builtin_amdgcn_readfirstlane(n0);   // wave-uniform -> SGPR
    const int lane = threadIdx.x & 63;
    const int q = lane >> 4, r = lane & 15;
    const int r16 = r << 4;
    const char* hbase = (const char*)hb;
    const float epsv = 1.0f + epsp[0];
    const uint4v sv = *(const uint4v*)(hbase + (((unsigned)n << 8) + r16));
    int b0[KK], dg[KK], cv[KK];
    #pragma unroll
    for (int k = 0; k < KK; ++k) {
        int a = rp[k*(NV+1) + n];
        int b = rp[k*(NV+1) + n + 1];
        b0[k] = a; dg[k] = b - a;
        cv[k] = (lane < dg[k]) ? col[(size_t)k*EE + a + lane] : NV;  // NV = zero row
    }
    f32x2 acc[KK][4];
    #pragma unroll
    for (int k = 0; k < KK; ++k)
        #pragma unroll
        for (int c = 0; c < 4; ++c) acc[k][c] = (f32x2){0.f, 0.f};
    #pragma unroll
    for (int k = 0; k < KK; ++k) {
        const int dc = min(dg[k], 64);            // wave-uniform bound
        for (int base = 0; base < dc; base += 8) {
            int s0 = __shfl(cv[k], base + q);      // lanes all active; idx <= 63
            int s1 = __shfl(cv[k], base + q + 4);
            uint4v v0 = *(const uint4v*)(hbase + (((unsigned)s0 << 8) + r16));
            uint4v v1 = *(const uint4v*)(hbase + (((unsigned)s1 << 8) + r16));
            #pragma unroll
            for (int c = 0; c < 4; ++c) {
                acc[k][c] += up2(v0[c]);
                acc[k][c] += up2(v1[c]);
            }
        }
        // deg > 64 tail: direct col loads (no cross-lane ops)
        for (int j = b0[k] + 64 + q; j < b0[k] + dg[k]; j += 4) {
            int s0 = col[(size_t)k*EE + j];
            uint4v v0 = *(const uint4v*)(hbase + (((unsigned)s0 << 8) + r16));
            #pragma unroll
            for (int c = 0; c < 4; ++c) acc[k][c] += up2(v0[c]);
        }
    }
    #pragma unroll
    for (int k = 0; k < KK; ++k) {
        #pragma unroll
        for (int c = 0; c < 4; ++c) {
            acc[k][c][0] += __shfl_xor(acc[k][c][0], 16);
            acc[k][c][1] += __shfl_xor(acc[k][c][1], 16);
            acc[k][c][0] += __shfl_xor(acc[k][c][0], 32);
            acc[k][c][1] += __shfl_xor(acc[k][c][1], 32);
        }
    }
    if (q == 0) {
        // fragment-tiled store: granule r of node n ->
        //   k*NV*256 + (n>>4)*4096 + r*256 + (n&15)*16
        const unsigned dsto = (((unsigned)n >> 4) << 12) + ((unsigned)r << 8)
                            + (((unsigned)n & 15u) << 4);
        #pragma unroll
        for (int k = 0; k < KK; ++k) {
            uint4v pk;
            #pragma unroll
            for (int c = 0; c < 4; ++c) {
                f32x2 s2 = up2(sv[c]);
                float lo = acc[k][c][0] + epsv * s2[0];
                float hi = acc[k][c][1] + epsv * s2[1];
                unsigned int pko;
                asm("v_cvt_pk_bf16_f32 %0, %1, %2" : "=v"(pko) : "v"(lo), "v"(hi));
                pk[c] = pko;
            }
            *(uint4v*)((char*)zin + (size_t)k*NV*256 + dsto) = pk;
        }
    }
}

// BN1 stats of z1_k = zin_k @ W1 for ALL relations (looped inside; W1 staged
// once per block). Grid 256 so staging traffic is 256x64KB.
__launch_bounds__(256, 2)
__global__ void k_stats3(const unsigned short* __restrict__ zin,
                         const unsigned short* __restrict__ w1f,
                         float* __restrict__ statsL) {
    __shared__ __align__(16) unsigned short bfr1[32768];  // 64KB W1 frags
    __shared__ float scf[1024];
    const int t = threadIdx.x;
    for (int i = t; i < 4096; i += 256)
        *(uint4v*)(bfr1 + i*8) = *(const uint4v*)(w1f + i*8);
    const int lane = t & 63, w = t >> 6;
    const int r_ = lane & 15, g = lane >> 4;
    const int rt = w & 1, ch = w >> 1;
    __syncthreads();
    for (int krel = 0; krel < KK; ++krel) {
        const char* zk = (const char*)zin + (size_t)krel*NV*256;
        float ssum[8] = {0,0,0,0,0,0,0,0};
        float ssq[8]  = {0,0,0,0,0,0,0,0};
        for (int tile = blockIdx.x; tile < NV/32; tile += gridDim.x) {
            short8 af[4];
            #pragma unroll
            for (int kt = 0; kt < 4; ++kt)
                af[kt] = *(const short8*)(zk + (size_t)(tile*2 + rt)*4096 + kt*1024 + lane*16);
            #pragma unroll
            for (int ct = 0; ct < 8; ++ct) {
                const int ntg = ch*8 + ct;
                f32x4 c = {0.f,0.f,0.f,0.f};
                #pragma unroll
                for (int kt = 0; kt < 4; ++kt) {
                    short8 b = *(const short8*)(bfr1 + ((size_t)((kt*16 + ntg)*64 + lane))*8);
                    c = __builtin_amdgcn_mfma_f32_16x16x32_bf16(af[kt], b, c, 0, 0, 0);
                }
                float s = c[0]+c[1]+c[2]+c[3];
                float q = c[0]*c[0]+c[1]*c[1]+c[2]*c[2]+c[3]*c[3];
                s += __shfl_xor(s, 16); q += __shfl_xor(q, 16);
                s += __shfl_xor(s, 32); q += __shfl_xor(q, 32);
                ssum[ct] += s; ssq[ct] += q;
            }
        }
        __syncthreads();   // prior krel's atomics done reading scf
        if (g == 0) {
            #pragma unroll
            for (int ct = 0; ct < 8; ++ct) {
                const int colc = (ch*8 + ct)*16 + r_;
                scf[rt*256 + colc]       = ssum[ct];
                scf[512 + rt*256 + colc] = ssq[ct];
            }
        }
        __syncthreads();
        atomicAdd(statsL + ZS(krel) + t, scf[t]       + scf[256 + t]);
        atomicAdd(statsL + ZQ(krel) + t, scf[512 + t] + scf[768 + t]);
    }
}

// hn = [ sum_k relu(A''_k (zin_k @ W1) + B''_k) ] @ W2 + hn column stats.
// R5-proven structure (8 waves, W1+W2 LDS 128KB, single 16KB yt); af loads
// 1KB coalesced via the fragment-tiled zin layout. BN1 affine inline.
__launch_bounds__(512, 2)
__global__ void k_gemm2f(const unsigned short* __restrict__ zin,
                         const unsigned short* __restrict__ w1f,
                         const unsigned short* __restrict__ w2f,
                         const float* __restrict__ g1l, const float* __restrict__ be1l,
                         const float* __restrict__ params,
                         float* __restrict__ statsL,
                         unsigned short* __restrict__ hnb) {
    __shared__ __align__(16) unsigned short bfr1[32768];  // 64KB W1 frags
    __shared__ __align__(16) unsigned short bfr2[32768];  // 64KB W2 frags
    __shared__ __align__(16) unsigned char yt[16384];     // 32 x 256 bf16, swizzled
    const int t = threadIdx.x;
    for (int i = t; i < 4096; i += 512)
        *(uint4v*)(bfr1 + i*8) = *(const uint4v*)(w1f + i*8);
    for (int i = t; i < 4096; i += 512)
        *(uint4v*)(bfr2 + i*8) = *(const uint4v*)(w2f + i*8);
    const int lane = t & 63, w = t >> 6;          // 8 waves
    const int r_ = lane & 15, g = lane >> 4;
    const int rt = w & 1, ch = w >> 1;            // rt: row half, ch: col quarter
    const int arow = rt*16 + r_;
    // BN1 affine (a_k folded) computed inline from raw column stats
    float pa1[KK][4], pb1[KK][4];
    #pragma unroll
    for (int k = 0; k < KK; ++k) {
        const float ak = params[k];
        #pragma unroll
        for (int ct = 0; ct < 4; ++ct) {
            const int colc = (ch*4 + ct)*16 + r_;
            float mu  = statsL[ZS(k) + colc] * (1.0f/NV);
            float var = statsL[ZQ(k) + colc] * (1.0f/NV) - mu*mu;
            float A = g1l[colc] * rsqrtf(var + 1e-5f);
            pa1[k][ct] = ak * A;
            pb1[k][ct] = ak * (be1l[colc] - mu*A);
        }
    }
    __syncthreads();
    float ssum[2] = {0,0}, ssq[2] = {0,0};
    for (int tile = blockIdx.x; tile < NV/32; tile += gridDim.x) {
        const int row0 = tile*32;
        // phase 1: y = sum_k relu(BN1_k(zin_k @ W1)); af coalesced 1KB loads
        f32x4 y[4];
        #pragma unroll
        for (int ct = 0; ct < 4; ++ct) y[ct] = (f32x4){0.f,0.f,0.f,0.f};
        short8 af[KK][4];
        #pragma unroll
        for (int k = 0; k < KK; ++k) {
            #pragma unroll
            for (int kt = 0; kt < 4; ++kt)
                af[k][kt] = *(const short8*)((const char*)zin + (size_t)k*NV*256
                              + (size_t)(tile*2 + rt)*4096 + kt*1024 + lane*16);
        }
        #pragma unroll
        for (int k = 0; k < KK; ++k) {
            #pragma unroll
            for (int ct = 0; ct < 4; ++ct) {
                const int ntg = ch*4 + ct;
                f32x4 c = {0.f,0.f,0.f,0.f};
                #pragma unroll
                for (int kt = 0; kt < 4; ++kt) {
                    short8 b = *(const short8*)(bfr1 + ((size_t)((kt*16 + ntg)*64 + lane))*8);
                    c = __builtin_amdgcn_mfma_f32_16x16x32_bf16(af[k][kt], b, c, 0, 0, 0);
                }
                #pragma unroll
                for (int reg = 0; reg < 4; ++reg)
                    y[ct][reg] += fmaxf(pa1[k][ct]*c[reg] + pb1[k][ct], 0.0f);
            }
        }
        __syncthreads();   // prev phase2 done reading yt
        #pragma unroll
        for (int ct = 0; ct < 4; ++ct) {
            const int col2 = ((ch*4 + ct)*16 + r_)*2;
            #pragma unroll
            for (int reg = 0; reg < 4; ++reg) {
                const int row = rt*16 + g*4 + reg;
                *(unsigned short*)(yt + row*512 + (col2 ^ ((row & 15) << 4))) = f2bf(y[ct][reg]);
            }
        }
        __syncthreads();
        // phase 2: hn = y @ W2 (W2 from LDS)
        short8 ya[8];
        #pragma unroll
        for (int kt = 0; kt < 8; ++kt)
            ya[kt] = *(const short8*)(yt + arow*512 + ((kt*64 + g*16) ^ ((arow & 15) << 4)));
        #pragma unroll
        for (int ct2 = 0; ct2 < 2; ++ct2) {
            const int ntg2 = ch*2 + ct2;
            f32x4 c = {0.f,0.f,0.f,0.f};
            #pragma unroll
            for (int kt = 0; kt < 8; ++kt) {
                short8 b = *(const short8*)(bfr2 + ((size_t)((kt*8 + ntg2)*64 + lane))*8);
                c = __builtin_amdgcn_mfma_f32_16x16x32_bf16(ya[kt], b, c, 0, 0, 0);
            }
            unsigned short* hp = hnb + (size_t)(row0 + rt*16 + g*4)*DD + ntg2*16 + r_;
            float ps = 0.0f, pq = 0.0f;
            #pragma unroll
            for (int reg = 0; reg < 4; ++reg) {
                float xv = c[reg];
                hp[(size_t)reg*DD] = f2bf(xv);
                ps += xv; pq += xv*xv;
            }
            ps += __shfl_xor(ps, 16); pq += __shfl_xor(pq, 16);
            ps += __shfl_xor(ps, 32); pq += __shfl_xor(pq, 32);
            ssum[ct2] += ps; ssq[ct2] += pq;
        }
    }
    // flush hn column stats (reuse yt; wave w covers cols ch*32 .. ch*32+31)
    __syncthreads();
    float* scf = (float*)yt;
    if (g == 0) {
        #pragma unroll
        for (int ct2 = 0; ct2 < 2; ++ct2) {
            scf[w*32 + ct2*16 + r_]       = ssum[ct2];
            scf[256 + w*32 + ct2*16 + r_] = ssq[ct2];
        }
    }
    __syncthreads();
    if (t < 128) {
        const int chc = t >> 5, idx = t & 31;
        float s = 0.0f, q = 0.0f;
        #pragma unroll
        for (int rr = 0; rr < 2; ++rr) {
            s += scf[(chc*2 + rr)*32 + idx];
            q += scf[256 + (chc*2 + rr)*32 + idx];
        }
        atomicAdd(statsL + HSUM + t, s);
        atomicAdd(statsL + HSQ + t, q);
    }
}

// mid layers: h(bf16) = relu(BN2(hn)); BN2 affine computed inline from stats
__global__ void k_bnapply_mid(const unsigned short* __restrict__ hnb,
                              const float* __restrict__ statsL,
                              const float* __restrict__ bng, const float* __restrict__ bnb,
                              unsigned short* __restrict__ hb) {
    int id = blockIdx.x*256 + threadIdx.x;       // 6250 blocks * 8 elems
    const int col0 = (id & 15)*8;
    short8 v = *(const short8*)(hnb + (size_t)id*8);
    short8 o;
    #pragma unroll
    for (int j = 0; j < 8; ++j) {
        const int c = col0 + j;
        float mu  = statsL[HSUM + c] * (1.0f/NV);
        float var = statsL[HSQ + c] * (1.0f/NV) - mu*mu;
        float A = bng[c] * rsqrtf(var + 1e-5f);
        float B = bnb[c] - mu*A;
        o[j] = (short)f2bf(fmaxf(A*bf2f((unsigned short)v[j]) + B, 0.0f));
    }
    *(short8*)(hb + (size_t)id*8) = o;
}

// final layer: d_out(f32) = relu(BN2(hn))
__global__ void k_bnapply_fin(const unsigned short* __restrict__ hnb,
                              const float* __restrict__ statsL,
                              const float* __restrict__ bng, const float* __restrict__ bnb,
                              float* __restrict__ out) {
    int id = blockIdx.x*256 + threadIdx.x;
    const int col0 = (id & 15)*8;
    short8 v = *(const short8*)(hnb + (size_t)id*8);
    f32x4 o0, o1;
    #pragma unroll
    for (int j = 0; j < 8; ++j) {
        const int c = col0 + j;
        float mu  = statsL[HSUM + c] * (1.0f/NV);
        float var = statsL[HSQ + c] * (1.0f/NV) - mu*mu;
        float A = bng[c] * rsqrtf(var + 1e-5f);
        float B = bnb[c] - mu*A;
        float r = fmaxf(A*bf2f((unsigned short)v[j]) + B, 0.0f);
        if (j < 4) o0[j] = r; else o1[j-4] = r;
    }
    *(f32x4*)(out + (size_t)id*8)     = o0;
    *(f32x4*)(out + (size_t)id*8 + 4) = o1;
}

extern "C" void kernel_launch(void* const* d_in, const int* in_sizes, int n_in,
                              void* d_out, int out_size, void* d_ws, size_t ws_size,
                              hipStream_t stream) {
    const int*   x     = (const int*)d_in[0];
    const int*   ke    = (const int*)d_in[1];
    const float* emb   = (const float*)d_in[2];
    const float* W1    = (const float*)d_in[3];
    // d_in[4] = b1: per-column shift cancels exactly through training-mode BN
    const float* g1    = (const float*)d_in[5];
    const float* be1   = (const float*)d_in[6];
    const float* W2    = (const float*)d_in[7];
    // d_in[8] = b2: cancels through final BN (softmax weights sum to 1)
    const float* eps   = (const float*)d_in[9];
    const float* alpha = (const float*)d_in[10];
    const float* bng   = (const float*)d_in[11];
    const float* bnb   = (const float*)d_in[12];

    char* ws = (char*)d_ws;
    unsigned short* hb     = (unsigned short*)(ws + HB_OFF);
    unsigned short* zin    = (unsigned short*)(ws + ZIN_OFF);   // 3 buffers, tiled
    unsigned short* hnb    = (unsigned short*)(ws + HNB_OFF);
    size_t o = O_BASE;
    unsigned short* w1f    = (unsigned short*)(ws + o);          o += 3*65536;
    unsigned short* w2f    = (unsigned short*)(ws + o);          o += 3*65536;
    float*          stats  = (float*)(ws + o);                   o += 32768;  // 3 x 2048 floats
    float*          params = (float*)(ws + o);                   o += 4096;
    int*            rp     = (int*)(ws + o);                     o += 1200128;
    int*            col    = (int*)(ws + o);                     o += 7200000;
    int*            cur    = (int*)(ws + o);                     o += 4096;
    int*            ebase  = (int*)(ws + o);                     o += 4096;
    unsigned int*   pairs  = (unsigned int*)(ws + ZIN_OFF);      // aliased (pre-zin)

    // AtomEncoder (+ zero-pad rows NV..NV+7 for the gather dummy row)
    k_embed<<<12501, 256, 0, stream>>>(x, emb, hb);

    // Weight prep for ALL layers (single dispatch, off the per-layer path)
    k_prep_all<<<dim3(32, LL), 256, 0, stream>>>(W1, W2, alpha, w1f, w2f, params);

    // CSR build (shared by all layers; uses pairs alias before any zin write)
    hipMemsetAsync(cur, 0, KK*NBKT*sizeof(int), stream);
    hipMemsetAsync(stats, 0, 3*2048*sizeof(float), stream);   // all layers' stats
    kA_bin<<<dim3(147, KK), 256, 0, stream>>>(ke, cur, pairs);
    kB_scan<<<1, 256, 0, stream>>>(cur, ebase);
    kB_fill<<<dim3(NBKT, KK), 256, 0, stream>>>(pairs, cur, ebase, rp, col);

    for (int l = 0; l < LL; ++l) {
        float* statsL = stats + (size_t)l*2048;
        unsigned short* w1fl = w1f + (size_t)l*32768;
        unsigned short* w2fl = w2f + (size_t)l*32768;
        k_gather3<<<25000, 256, 0, stream>>>(hb, rp, col, eps + l, zin);
        k_stats3<<<256, 256, 0, stream>>>(zin, w1fl, statsL);
        k_gemm2f<<<256, 512, 0, stream>>>(zin, w1fl, w2fl, g1 + l*D2, be1 + l*D2,
                                          params + l*4, statsL, hnb);
        if (l < LL-1) k_bnapply_mid<<<6250, 256, 0, stream>>>(hnb, statsL,
                                                              bng + l*DD, bnb + l*DD, hb);
        else          k_bnapply_fin<<<6250, 256, 0, stream>>>(hnb, statsL,
                                                              bng + l*DD, bnb + l*DD,
                                                              (float*)d_out);
    }
}